// Round 9
// baseline (313.284 us; speedup 1.0000x reference)
//
#include <hip/hip_runtime.h>
#include <cstdint>
#include <cstddef>

#define NNODES 50000
#define HD 256
#define NCH 3
#define BM 64

typedef __attribute__((ext_vector_type(8))) short shortx8;
typedef __attribute__((ext_vector_type(4))) float floatx4;
typedef __attribute__((ext_vector_type(16))) float floatx16;

__device__ __forceinline__ unsigned short f2bf(float x) {
    union { float f; uint32_t u; } v; v.f = x;
    uint32_t r = v.u + 0x7fffu + ((v.u >> 16) & 1u);   // RNE
    return (unsigned short)(r >> 16);
}
// packed f32x2 -> bf16x2 (dst.lo = bf16(a), dst.hi = bf16(b))
__device__ __forceinline__ uint32_t cvtpk(float a, float b) {
    uint32_t r;
    asm("v_cvt_pk_bf16_f32 %0, %1, %2" : "=v"(r) : "v"(a), "v"(b));
    return r;
}
__device__ __forceinline__ shortx8 cvt8(float4 a, float4 b) {
    union { uint32_t u[4]; shortx8 v; } o;
    o.u[0] = cvtpk(a.x, a.y);
    o.u[1] = cvtpk(a.z, a.w);
    o.u[2] = cvtpk(b.x, b.y);
    o.u[3] = cvtpk(b.z, b.w);
    return o.v;
}
__device__ __forceinline__ float sigf(float x) {
    return 1.0f / (1.0f + __expf(-x));
}
__device__ __forceinline__ float tanhfast(float x) {
    return 1.0f - 2.0f / (__expf(2.0f * x) + 1.0f);
}
__device__ __forceinline__ floatx16 mfma32(shortx8 a, shortx8 b, floatx16 c) {
    return __builtin_amdgcn_mfma_f32_32x32x16_bf16(a, b, c, 0, 0, 0);
}

// ---------------------------------------------------------------------------
// Pre-pass: weights fp32 [out,in] -> bf16 fragments for 32x32x16 MFMA.
// fi = ((d*32 + tile)*16 + ks)*64 + lane ; 8 bf16 each.
// tile 0..7 -> U_f cols; 8..15 -> I; 16..23 -> O; 24..31 -> U (32-wide tiles)
// lane l: wcol = tile*32 + (l&31), k = ks*16 + (l>>5)*8 + e
// ---------------------------------------------------------------------------
__global__ void prep_weights32(const float* __restrict__ U_f,
                               const float* __restrict__ U_iou,
                               unsigned short* __restrict__ wsB) {
    int idx = blockIdx.x * 256 + threadIdx.x;   // 98304 frags
    int lane = idx & 63;
    int ks   = (idx >> 6) & 15;
    int tile = (idx >> 10) & 31;
    int d    = idx >> 15;
    if (d >= NCH) return;
    int col = tile * 32 + (lane & 31);
    int k0  = ks * 16 + (lane >> 5) * 8;
    const float* src = (col < 256)
        ? (U_f   + (((size_t)d * 256 + col)         * 256 + k0))
        : (U_iou + (((size_t)d * 768 + (col - 256)) * 256 + k0));
    shortx8 o;
    #pragma unroll
    for (int e = 0; e < 8; ++e) o[e] = (short)f2bf(src[e]);
    reinterpret_cast<shortx8*>(wsB)[idx] = o;
}

// ---------------------------------------------------------------------------
// Main kernel (r8 structure, BM doubled): mfma_f32_32x32x16_bf16 with
// A = weight tile (32 wcols), B = nh (32 nodes). Lane holds node = lane&31,
// 16 wcols in 4 float4-aligned quads -> register-only fold/epilogue.
// 1024 thr = 16 waves = 8 col-groups x 2 node-tiles, BM=64 nodes/block.
// Halving the block count halves the per-block weight L2 re-read (the r8
// limiter), and wave-pairs (w, w+8) share fragment streams via L1/L2.
// 96 KiB dynamic LDS (3 children nh, 16B-chunk XOR swizzle), ONE barrier.
// 1024-thr blocks force <=128 regs -> 16 waves/CU; f_in is re-read per
// child (L3-resident) instead of held in registers to stay under the cap.
// ---------------------------------------------------------------------------
__global__ __launch_bounds__(1024) void treelstm_main(
    const float* __restrict__ nh,       // [N][3][256]
    const float* __restrict__ ncc,      // [N][3][256]
    const float* __restrict__ f_in,     // [N][256]
    const float* __restrict__ iou_in,   // [N][768]
    const unsigned short* __restrict__ wsB,
    float* __restrict__ out)            // h [N][256] then c [N][256]
{
    extern __shared__ unsigned short sA[];   // NCH*BM*32*8 bf16 = 96 KiB

    const int tid  = threadIdx.x;
    const int nb   = blockIdx.x * BM;
    const int lane = tid & 63;
    const int w    = tid >> 6;        // 0..15
    const int cg   = w & 7;           // col window [cg*32, +32)
    const int nt   = w >> 3;          // node tile 0/1
    const int nl   = lane & 31;
    const int hi   = lane >> 5;
    const int colb = cg * 32 + hi * 4;   // cols colb + 8q + r
    const int node = nt * 32 + nl;       // 0..63 within block

    const shortx8* Bfr = reinterpret_cast<const shortx8*>(wsB);

    // ---- stage all 3 children's nh: coalesced reads, swizzled chunks ----
    #pragma unroll
    for (int i = 0; i < 6; ++i) {
        int c     = i * 1024 + tid;       // 0..6143
        int d     = c >> 11;
        int nodeS = (c >> 5) & 63;
        int slot  = c & 31;
        int gn    = nb + nodeS;
        shortx8 o;
        if (gn < NNODES) {
            const float4* q = reinterpret_cast<const float4*>(
                nh + ((size_t)gn * (NCH * HD) + d * HD + slot * 8));
            o = cvt8(q[0], q[1]);
        } else {
            #pragma unroll
            for (int e = 0; e < 8; ++e) o[e] = 0;
        }
        int idx = (d * BM + nodeS) * 32 + (slot ^ (nodeS & 7));
        *reinterpret_cast<shortx8*>(&sA[idx * 8]) = o;
    }
    __syncthreads();          // the ONLY barrier

    const int  n     = nb + node;
    const bool valid = (n < NNODES);
    const int  nc_   = valid ? n : (NNODES - 1);

    float cagg[16];
    #pragma unroll
    for (int t = 0; t < 16; ++t) cagg[t] = 0.0f;

    floatx16 accI, accO, accU;
    #pragma unroll
    for (int t = 0; t < 16; ++t) { accI[t] = 0.0f; accO[t] = 0.0f; accU[t] = 0.0f; }

    const int nsw = node & 7;   // chunk swizzle for this thread's node row

    #pragma unroll 1
    for (int d = 0; d < NCH; ++d) {
        floatx16 accF;
        #pragma unroll
        for (int t = 0; t < 16; ++t) accF[t] = 0.0f;

        #pragma unroll 2
        for (int ks = 0; ks < 16; ++ks) {
            shortx8 aF = Bfr[((d * 32 +      cg) * 16 + ks) * 64 + lane];
            shortx8 aI = Bfr[((d * 32 +  8 + cg) * 16 + ks) * 64 + lane];
            shortx8 aO = Bfr[((d * 32 + 16 + cg) * 16 + ks) * 64 + lane];
            shortx8 aU = Bfr[((d * 32 + 24 + cg) * 16 + ks) * 64 + lane];
            int ch = (ks * 2 + hi) ^ nsw;
            shortx8 b = *reinterpret_cast<const shortx8*>(
                &sA[((d * BM + node) * 32 + ch) * 8]);
            accF = mfma32(aF, b, accF);
            accI = mfma32(aI, b, accI);
            accO = mfma32(aO, b, accO);
            accU = mfma32(aU, b, accU);
        }

        // ---- fold: cagg += sigmoid(F + f_in) * nc  (registers, float4) ----
        #pragma unroll
        for (int q = 0; q < 4; ++q) {
            floatx4 ncr = *reinterpret_cast<const floatx4*>(
                ncc + (size_t)nc_ * (NCH * HD) + d * HD + colb + q * 8);
            floatx4 fi4 = *reinterpret_cast<const floatx4*>(
                f_in + (size_t)nc_ * HD + colb + q * 8);
            #pragma unroll
            for (int r = 0; r < 4; ++r)
                cagg[q * 4 + r] +=
                    sigf(accF[q * 4 + r] + fi4[r]) * ncr[r];
        }
    }

    // ---- epilogue: one node per thread, 4 float4 quads, no syncs ----
    if (valid) {
        #pragma unroll
        for (int q = 0; q < 4; ++q) {
            int col = colb + q * 8;
            size_t base = (size_t)n * 768 + col;
            floatx4 i4 = *reinterpret_cast<const floatx4*>(iou_in + base);
            floatx4 o4 = *reinterpret_cast<const floatx4*>(iou_in + base + 256);
            floatx4 u4 = *reinterpret_cast<const floatx4*>(iou_in + base + 512);
            floatx4 cc, hh;
            #pragma unroll
            for (int r = 0; r < 4; ++r) {
                int t = q * 4 + r;
                float iv = accI[t] + 2.0f * i4[r];
                float ov = accO[t] + 2.0f * o4[r];
                float uv = accU[t] + 2.0f * u4[r];
                float c  = sigf(iv) * tanhfast(uv) + cagg[t];
                cc[r] = c;
                hh[r] = sigf(ov) * tanhfast(c);
            }
            *reinterpret_cast<floatx4*>(out + (size_t)n * HD + col) = hh;
            *reinterpret_cast<floatx4*>(out + (size_t)(NNODES + n) * HD + col) = cc;
        }
    }
}

extern "C" void kernel_launch(void* const* d_in, const int* in_sizes, int n_in,
                              void* d_out, int out_size, void* d_ws, size_t ws_size,
                              hipStream_t stream) {
    const float* nh     = (const float*)d_in[0];
    const float* ncc    = (const float*)d_in[1];
    const float* f_in   = (const float*)d_in[2];
    const float* iou_in = (const float*)d_in[3];
    const float* U_f    = (const float*)d_in[4];
    const float* U_iou  = (const float*)d_in[5];
    unsigned short* wsB = (unsigned short*)d_ws;

    if (ws_size < (size_t)(3 * 32 * 16 * 64) * 16) return;

    hipLaunchKernelGGL(prep_weights32, dim3(384), dim3(256), 0, stream,
                       U_f, U_iou, wsB);
    hipLaunchKernelGGL(treelstm_main, dim3((NNODES + BM - 1) / BM), dim3(1024),
                       NCH * BM * 32 * 8 * sizeof(unsigned short), stream,
                       nh, ncc, f_in, iou_in, wsB, (float*)d_out);
}